// Round 1
// baseline (229.777 us; speedup 1.0000x reference)
//
#include <hip/hip_runtime.h>

// Problem constants (reference: H = W = 2048, C = 8, N = 1e6)
#define HH 2048
#define WW 2048
#define CC 8
#define MODV 2044.0f   // H - 4

typedef float f32x2 __attribute__((ext_vector_type(2)));
typedef float f32x4 __attribute__((ext_vector_type(4)));

// Bilinear combine for 4 channels at once (ext_vector broadcasts scalars).
// Reference naming (follow the code, not the names):
//   tl = V[i0][i1], tr = V[i0+1][i1], bl = V[i0][i1+1], br = V[i0+1][i1+1]
//   mb = br + d0*(bl-br); mt = tr + d0*(tl-tr); out = mb + d1*(mt-mb)
__device__ __forceinline__ f32x4 blerp4(f32x4 tl, f32x4 tr, f32x4 bl, f32x4 br,
                                        float d0, float d1, float m) {
    f32x4 mb = br + d0 * (bl - br);
    f32x4 mt = tr + d0 * (tl - tr);
    return m * (mb + d1 * (mt - mb));
}

// c = (coord - 1) mod 2044 + 1 (floored mod); returns base ptr of V[i0][i1]
__device__ __forceinline__ const float* point_addr(f32x2 co, const float* visible,
                                                   float& d0, float& d1, float& m) {
    float x = co.x - 1.0f;
    float y = co.y - 1.0f;
    float cx = fmodf(x, MODV); if (cx < 0.0f) cx += MODV;
    float cy = fmodf(y, MODV); if (cy < 0.0f) cy += MODV;
    cx += 1.0f;
    cy += 1.0f;
    float fx = floorf(cx);
    float fy = floorf(cy);
    d0 = cx - fx;               // delta along dim 0 (rows)
    d1 = cy - fy;               // delta along dim 1 (cols)
    int i0 = (int)fx;           // row index in [1, 2044]
    int i1 = (int)fy;           // col index in [1, 2044]
    // off = c > dims (unreachable since c < 2045; kept for fidelity)
    m = (cx > (float)HH) ? 0.0f : 1.0f;
    return visible + ((size_t)i0 * WW + (size_t)i1) * CC;
}

// Two independent points per thread: 16 gathers issued before any use so the
// wave has 2x outstanding misses; A-compute overlaps B-load tail (vmcnt(8)).
__global__ __launch_bounds__(256) void idx2pixel_kernel(
    const float* __restrict__ coords,   // (N, 2)
    const float* __restrict__ visible,  // (H, W, C) row-major
    float* __restrict__ out,            // (N, C)
    int n)
{
    int t = blockIdx.x * blockDim.x + threadIdx.x;
    int half = (n + 1) >> 1;
    if (t >= half) return;
    int tb = t + half;
    bool hasB = (tb < n);
    int tbc = hasB ? tb : t;   // clamp for safe (masked) second point

    // coords: streamed once, never reused -> non-temporal (don't pollute L2)
    f32x2 coA = __builtin_nontemporal_load(reinterpret_cast<const f32x2*>(coords) + t);
    f32x2 coB = __builtin_nontemporal_load(reinterpret_cast<const f32x2*>(coords) + tbc);

    float d0A, d1A, mA, d0B, d1B, mB;
    const float* pA   = point_addr(coA, visible, d0A, d1A, mA);
    const float* pB   = point_addr(coB, visible, d0B, d1B, mB);
    const float* pA10 = pA + (size_t)WW * CC;   // row + 1
    const float* pB10 = pB + (size_t)WW * CC;

    // ---- issue all 16 gathers back-to-back (A first, then B) ----
    // layout per row-segment: [i1 pixel: 8 floats][i1+1 pixel: 8 floats] = 64B
    f32x4 Atl0 = *(const f32x4*)(pA);
    f32x4 Atl1 = *(const f32x4*)(pA + 4);
    f32x4 Abl0 = *(const f32x4*)(pA + 8);        // col+1, contiguous
    f32x4 Abl1 = *(const f32x4*)(pA + 12);
    f32x4 Atr0 = *(const f32x4*)(pA10);
    f32x4 Atr1 = *(const f32x4*)(pA10 + 4);
    f32x4 Abr0 = *(const f32x4*)(pA10 + 8);
    f32x4 Abr1 = *(const f32x4*)(pA10 + 12);

    f32x4 Btl0 = *(const f32x4*)(pB);
    f32x4 Btl1 = *(const f32x4*)(pB + 4);
    f32x4 Bbl0 = *(const f32x4*)(pB + 8);
    f32x4 Bbl1 = *(const f32x4*)(pB + 12);
    f32x4 Btr0 = *(const f32x4*)(pB10);
    f32x4 Btr1 = *(const f32x4*)(pB10 + 4);
    f32x4 Bbr0 = *(const f32x4*)(pB10 + 8);
    f32x4 Bbr1 = *(const f32x4*)(pB10 + 12);

    // ---- point A: compute + store (overlaps B load tail) ----
    f32x4 oA0 = blerp4(Atl0, Atr0, Abl0, Abr0, d0A, d1A, mA);
    f32x4 oA1 = blerp4(Atl1, Atr1, Abl1, Abr1, d0A, d1A, mA);
    float* poA = out + (size_t)t * CC;
    __builtin_nontemporal_store(oA0, (f32x4*)poA);       // out never re-read
    __builtin_nontemporal_store(oA1, (f32x4*)(poA + 4));

    // ---- point B ----
    f32x4 oB0 = blerp4(Btl0, Btr0, Bbl0, Bbr0, d0B, d1B, mB);
    f32x4 oB1 = blerp4(Btl1, Btr1, Bbl1, Bbr1, d0B, d1B, mB);
    if (hasB) {
        float* poB = out + (size_t)tb * CC;
        __builtin_nontemporal_store(oB0, (f32x4*)poB);
        __builtin_nontemporal_store(oB1, (f32x4*)(poB + 4));
    }
}

extern "C" void kernel_launch(void* const* d_in, const int* in_sizes, int n_in,
                              void* d_out, int out_size, void* d_ws, size_t ws_size,
                              hipStream_t stream) {
    const float* coords  = (const float*)d_in[0];  // (N, 2) fp32
    const float* visible = (const float*)d_in[1];  // (2048, 2048, 8) fp32
    float* out = (float*)d_out;                    // (N, 8) fp32
    int n = in_sizes[0] / 2;

    int half = (n + 1) >> 1;
    int block = 256;
    int grid = (half + block - 1) / block;
    idx2pixel_kernel<<<grid, block, 0, stream>>>(coords, visible, out, n);
}

// Round 2
// 224.980 us; speedup vs baseline: 1.0213x; 1.0213x over previous
//
#include <hip/hip_runtime.h>

// Problem constants (reference: H = W = 2048, C = 8, N = 1e6)
#define HH 2048
#define WW 2048
#define CC 8
#define MODV 2044.0f   // H - 4

typedef float f32x2 __attribute__((ext_vector_type(2)));
typedef float f32x4 __attribute__((ext_vector_type(4)));

// Bilinear combine for 4 channels at once (ext_vector broadcasts scalars).
// Reference naming (follow the code, not the names):
//   tl = V[i0][i1], tr = V[i0+1][i1], bl = V[i0][i1+1], br = V[i0+1][i1+1]
//   mb = br + d0*(bl-br); mt = tr + d0*(tl-tr); out = mb + d1*(mt-mb)
__device__ __forceinline__ f32x4 blerp4(f32x4 tl, f32x4 tr, f32x4 bl, f32x4 br,
                                        float d0, float d1, float m) {
    f32x4 mb = br + d0 * (bl - br);
    f32x4 mt = tr + d0 * (tl - tr);
    return m * (mb + d1 * (mt - mb));
}

// c = (coord - 1) mod 2044 + 1 (floored mod); returns base ptr of V[i0][i1]
__device__ __forceinline__ const float* point_addr(f32x2 co, const float* visible,
                                                   float& d0, float& d1, float& m) {
    float x = co.x - 1.0f;
    float y = co.y - 1.0f;
    float cx = fmodf(x, MODV); if (cx < 0.0f) cx += MODV;
    float cy = fmodf(y, MODV); if (cy < 0.0f) cy += MODV;
    cx += 1.0f;
    cy += 1.0f;
    float fx = floorf(cx);
    float fy = floorf(cy);
    d0 = cx - fx;               // delta along dim 0 (rows)
    d1 = cy - fy;               // delta along dim 1 (cols)
    int i0 = (int)fx;           // row index in [1, 2044]
    int i1 = (int)fy;           // col index in [1, 2044]
    // off = c > dims (unreachable since c < 2045; kept for fidelity)
    m = (cx > (float)HH) ? 0.0f : 1.0f;
    return visible + ((size_t)i0 * WW + (size_t)i1) * CC;
}

// Four independent points per thread: 32 gathers issued before any use so each
// wave holds 32 outstanding loads; compute/store of A overlaps the B/C/D load
// tails. Plain (cached) loads/stores throughout — NT hints measured +24 MB
// FETCH / +4 MB WRITE on gfx950 (Round 1), reverted.
__global__ __launch_bounds__(64) void idx2pixel_kernel(
    const float* __restrict__ coords,   // (N, 2)
    const float* __restrict__ visible,  // (H, W, C) row-major
    float* __restrict__ out,            // (N, C)
    int n)
{
    int t = blockIdx.x * blockDim.x + threadIdx.x;
    int q = (n + 3) >> 2;
    if (t >= q) return;
    int tB = t + q, tC = t + 2 * q, tD = t + 3 * q;
    bool hB = tB < n, hC = tC < n, hD = tD < n;
    int iB = hB ? tB : t;   // clamp masked points to a safe address
    int iC = hC ? tC : t;
    int iD = hD ? tD : t;

    const f32x2* cp = reinterpret_cast<const f32x2*>(coords);
    f32x2 coA = cp[t];
    f32x2 coB = cp[iB];
    f32x2 coC = cp[iC];
    f32x2 coD = cp[iD];

    float d0A, d1A, mA, d0B, d1B, mB, d0C, d1C, mC, d0D, d1D, mD;
    const float* pA = point_addr(coA, visible, d0A, d1A, mA);
    const float* pB = point_addr(coB, visible, d0B, d1B, mB);
    const float* pC = point_addr(coC, visible, d0C, d1C, mC);
    const float* pD = point_addr(coD, visible, d0D, d1D, mD);
    const size_t RS = (size_t)WW * CC;   // row stride in floats

    // ---- issue all 32 gathers back-to-back ----
    // per row-segment layout: [i1 pixel: 8 floats][i1+1 pixel: 8 floats] = 64B
#define LD8(P, base)                                   \
    f32x4 P##tl0 = *(const f32x4*)(base);              \
    f32x4 P##tl1 = *(const f32x4*)((base) + 4);        \
    f32x4 P##bl0 = *(const f32x4*)((base) + 8);        \
    f32x4 P##bl1 = *(const f32x4*)((base) + 12);       \
    f32x4 P##tr0 = *(const f32x4*)((base) + RS);       \
    f32x4 P##tr1 = *(const f32x4*)((base) + RS + 4);   \
    f32x4 P##br0 = *(const f32x4*)((base) + RS + 8);   \
    f32x4 P##br1 = *(const f32x4*)((base) + RS + 12);

    LD8(A, pA)
    LD8(B, pB)
    LD8(C, pC)
    LD8(D, pD)
#undef LD8

    // ---- compute + store in issue order (A waits least, D's tail hidden) ----
    {
        f32x4 o0 = blerp4(Atl0, Atr0, Abl0, Abr0, d0A, d1A, mA);
        f32x4 o1 = blerp4(Atl1, Atr1, Abl1, Abr1, d0A, d1A, mA);
        float* po = out + (size_t)t * CC;
        *(f32x4*)po = o0;
        *(f32x4*)(po + 4) = o1;
    }
    {
        f32x4 o0 = blerp4(Btl0, Btr0, Bbl0, Bbr0, d0B, d1B, mB);
        f32x4 o1 = blerp4(Btl1, Btr1, Bbl1, Bbr1, d0B, d1B, mB);
        if (hB) {
            float* po = out + (size_t)tB * CC;
            *(f32x4*)po = o0;
            *(f32x4*)(po + 4) = o1;
        }
    }
    {
        f32x4 o0 = blerp4(Ctl0, Ctr0, Cbl0, Cbr0, d0C, d1C, mC);
        f32x4 o1 = blerp4(Ctl1, Ctr1, Cbl1, Cbr1, d0C, d1C, mC);
        if (hC) {
            float* po = out + (size_t)tC * CC;
            *(f32x4*)po = o0;
            *(f32x4*)(po + 4) = o1;
        }
    }
    {
        f32x4 o0 = blerp4(Dtl0, Dtr0, Dbl0, Dbr0, d0D, d1D, mD);
        f32x4 o1 = blerp4(Dtl1, Dtr1, Dbl1, Dbr1, d0D, d1D, mD);
        if (hD) {
            float* po = out + (size_t)tD * CC;
            *(f32x4*)po = o0;
            *(f32x4*)(po + 4) = o1;
        }
    }
}

extern "C" void kernel_launch(void* const* d_in, const int* in_sizes, int n_in,
                              void* d_out, int out_size, void* d_ws, size_t ws_size,
                              hipStream_t stream) {
    const float* coords  = (const float*)d_in[0];  // (N, 2) fp32
    const float* visible = (const float*)d_in[1];  // (2048, 2048, 8) fp32
    float* out = (float*)d_out;                    // (N, 8) fp32
    int n = in_sizes[0] / 2;

    int q = (n + 3) >> 2;     // points per slot (4 slots per thread)
    int block = 64;           // 1 wave/block: fine-grained CU balance
    int grid = (q + block - 1) / block;
    idx2pixel_kernel<<<grid, block, 0, stream>>>(coords, visible, out, n);
}